// Round 1
// baseline (8701.442 us; speedup 1.0000x reference)
//
#include <hip/hip_runtime.h>
#include <cstddef>

#define NB 64
#define TT 1024
#define DD 512
#define HH 512

// ---------------------------------------------------------------------------
// Kernel 1: out[n,t,:] = x[n,t,:] @ Wx + b   (M=N*T=65536, K=512, N=512)
// 128x128 tile, BK=8, 256 threads, 8x8 accumulator per thread. fp32 VALU.
// ---------------------------------------------------------------------------
#define BM 128
#define BN 128
#define BK 8

__global__ __launch_bounds__(256, 2) void gemm_xw(
    const float* __restrict__ A,     // (M, K) row-major
    const float* __restrict__ B,     // (K, H) row-major
    const float* __restrict__ bias,  // (H)
    float* __restrict__ C)           // (M, H)
{
    __shared__ float As[BK][BM];   // A tile stored transposed: As[k][m]
    __shared__ float Bs[BK][BN];

    const int tid  = threadIdx.x;
    const int tm   = tid >> 4;          // 0..15
    const int tn   = tid & 15;          // 0..15
    const int row0 = blockIdx.x * BM;
    const int col0 = blockIdx.y * BN;

    // A-tile load mapping: 128 rows x 8 cols, one float4 per thread
    const int ar = tid >> 1;            // 0..127
    const int ac = (tid & 1) * 4;       // 0 or 4
    // B-tile load mapping: 8 rows x 128 cols, one float4 per thread
    const int br = tid >> 5;            // 0..7
    const int bc = (tid & 31) * 4;      // 0..124

    float acc[8][8];
#pragma unroll
    for (int i = 0; i < 8; ++i)
#pragma unroll
        for (int j = 0; j < 8; ++j) acc[i][j] = 0.f;

    for (int k0 = 0; k0 < DD; k0 += BK) {
        float4 av = *reinterpret_cast<const float4*>(
            &A[(size_t)(row0 + ar) * DD + k0 + ac]);
        float4 bv = *reinterpret_cast<const float4*>(
            &B[(size_t)(k0 + br) * HH + col0 + bc]);

        As[ac + 0][ar] = av.x;
        As[ac + 1][ar] = av.y;
        As[ac + 2][ar] = av.z;
        As[ac + 3][ar] = av.w;
        *reinterpret_cast<float4*>(&Bs[br][bc]) = bv;
        __syncthreads();

#pragma unroll
        for (int kk = 0; kk < BK; ++kk) {
            float a[8], b[8];
            *reinterpret_cast<float4*>(&a[0]) =
                *reinterpret_cast<const float4*>(&As[kk][tm * 8]);
            *reinterpret_cast<float4*>(&a[4]) =
                *reinterpret_cast<const float4*>(&As[kk][tm * 8 + 4]);
            *reinterpret_cast<float4*>(&b[0]) =
                *reinterpret_cast<const float4*>(&Bs[kk][tn * 8]);
            *reinterpret_cast<float4*>(&b[4]) =
                *reinterpret_cast<const float4*>(&Bs[kk][tn * 8 + 4]);
#pragma unroll
            for (int i = 0; i < 8; ++i)
#pragma unroll
                for (int j = 0; j < 8; ++j)
                    acc[i][j] = fmaf(a[i], b[j], acc[i][j]);
        }
        __syncthreads();
    }

    // epilogue: add bias, store
#pragma unroll
    for (int i = 0; i < 8; ++i) {
        const int row = row0 + tm * 8 + i;
#pragma unroll
        for (int j = 0; j < 8; j += 4) {
            const int col = col0 + tn * 8 + j;
            float4 o;
            o.x = acc[i][j + 0] + bias[col + 0];
            o.y = acc[i][j + 1] + bias[col + 1];
            o.z = acc[i][j + 2] + bias[col + 2];
            o.w = acc[i][j + 3] + bias[col + 3];
            *reinterpret_cast<float4*>(&C[(size_t)row * HH + col]) = o;
        }
    }
}

// ---------------------------------------------------------------------------
// Kernel 2: sequential scan. One block per batch element n (64 blocks,
// 512 threads = one output column j per thread).
//   h_t[j] = tanh( sum_k h_{t-1}[k] * Wh[k][j] + xw[t][j] )
// xw lives in d_out (written by gemm_xw) and is overwritten in place by h_t.
// h is double-buffered in LDS; one __syncthreads per step.
// ---------------------------------------------------------------------------
__global__ __launch_bounds__(512, 2) void rnn_scan(
    const float* __restrict__ Wh,    // (H, H) row-major
    const float* __restrict__ h0,    // (N, H)
    float* __restrict__ out)         // (N, T, H): in = xw, out = h
{
    __shared__ float hbuf[2][HH];

    const int n = blockIdx.x;
    const int j = threadIdx.x;

    hbuf[0][j] = h0[(size_t)n * HH + j];
    __syncthreads();

    float* outn = out + (size_t)n * TT * HH;
    const float* __restrict__ wp = Wh + j;   // column j, stride HH

    int cur = 0;
    for (int t = 0; t < TT; ++t) {
        float acc = outn[(size_t)t * HH + j];   // xw[t][j]
        const float* hc = hbuf[cur];

#pragma unroll 4
        for (int k = 0; k < HH; k += 4) {
            float4 hv = *reinterpret_cast<const float4*>(&hc[k]);
            acc = fmaf(hv.x, wp[(size_t)(k + 0) * HH], acc);
            acc = fmaf(hv.y, wp[(size_t)(k + 1) * HH], acc);
            acc = fmaf(hv.z, wp[(size_t)(k + 2) * HH], acc);
            acc = fmaf(hv.w, wp[(size_t)(k + 3) * HH], acc);
        }

        float hn = tanhf(acc);
        outn[(size_t)t * HH + j] = hn;
        hbuf[cur ^ 1][j] = hn;
        cur ^= 1;
        __syncthreads();
    }
}

// ---------------------------------------------------------------------------
extern "C" void kernel_launch(void* const* d_in, const int* in_sizes, int n_in,
                              void* d_out, int out_size, void* d_ws, size_t ws_size,
                              hipStream_t stream) {
    const float* x  = (const float*)d_in[0];   // (N, T, D)
    const float* h0 = (const float*)d_in[1];   // (N, H)
    const float* Wx = (const float*)d_in[2];   // (D, H)
    const float* Wh = (const float*)d_in[3];   // (H, H)
    const float* b  = (const float*)d_in[4];   // (H)
    float* out = (float*)d_out;                // (N, T, H)

    dim3 g1((NB * TT) / BM, HH / BN);
    gemm_xw<<<g1, 256, 0, stream>>>(x, Wx, b, out);

    rnn_scan<<<NB, 512, 0, stream>>>(Wh, h0, out);
}

// Round 2
// 4600.483 us; speedup vs baseline: 1.8914x; 1.8914x over previous
//
#include <hip/hip_runtime.h>
#include <hip/hip_fp16.h>
#include <cstddef>
#include <cstdint>

#define NB 64
#define TT 1024
#define DD 512
#define HH 512
#define K2 256   // number of fp16 pairs per column (K=512)

// ---------------------------------------------------------------------------
// packed fp16 dot2 helper: acc += a.lo*b.lo + a.hi*b.hi   (fp32 accumulate)
// ---------------------------------------------------------------------------
typedef _Float16 h2_t __attribute__((ext_vector_type(2)));

__device__ __forceinline__ float dot2f(uint32_t a, uint32_t b, float c) {
#if __has_builtin(__builtin_amdgcn_fdot2)
    return __builtin_amdgcn_fdot2(__builtin_bit_cast(h2_t, a),
                                  __builtin_bit_cast(h2_t, b), c, false);
#else
    __half2 av = __builtin_bit_cast(__half2, a);
    __half2 bv = __builtin_bit_cast(__half2, b);
    float2 af = __half22float2(av), bf = __half22float2(bv);
    return fmaf(af.x, bf.x, fmaf(af.y, bf.y, c));
#endif
}

// ---------------------------------------------------------------------------
// Kernel 0: convert Wh (fp32, row-major 512x512) into packed fp16 pairs,
// swizzled so the scan's per-thread loads are dwordx4 and wave-coalesced:
//   Wt[((k2g*HH + j)*4) + q] = half2( Wh[2*k2][j], Wh[2*k2+1][j] ),
// where k2 = k2g*4 + q.   Size: 256*512 dwords = 512 KB (lives in d_ws).
// ---------------------------------------------------------------------------
__global__ void conv_wh(const float* __restrict__ Wh, uint32_t* __restrict__ Wt) {
    int tg = blockIdx.x * blockDim.x + threadIdx.x;   // 0..131071
    int k2 = tg >> 9;          // 0..255
    int j  = tg & (HH - 1);    // 0..511
    float w0 = Wh[(size_t)(2 * k2) * HH + j];
    float w1 = Wh[(size_t)(2 * k2 + 1) * HH + j];
    __half2 p = __floats2half2_rn(w0, w1);            // .x = w0 (low bits)
    int k2g = k2 >> 2, q = k2 & 3;
    Wt[((size_t)(k2g * HH + j) << 2) + q] = __builtin_bit_cast(uint32_t, p);
}

// ---------------------------------------------------------------------------
// Kernel 1: out[n,t,:] = x[n,t,:] @ Wx + b   (unchanged from round 1)
// ---------------------------------------------------------------------------
#define BM 128
#define BN 128
#define BK 8

__global__ __launch_bounds__(256, 2) void gemm_xw(
    const float* __restrict__ A,
    const float* __restrict__ B,
    const float* __restrict__ bias,
    float* __restrict__ C)
{
    __shared__ float As[BK][BM];
    __shared__ float Bs[BK][BN];

    const int tid  = threadIdx.x;
    const int tm   = tid >> 4;
    const int tn   = tid & 15;
    const int row0 = blockIdx.x * BM;
    const int col0 = blockIdx.y * BN;

    const int ar = tid >> 1;
    const int ac = (tid & 1) * 4;
    const int br = tid >> 5;
    const int bc = (tid & 31) * 4;

    float acc[8][8];
#pragma unroll
    for (int i = 0; i < 8; ++i)
#pragma unroll
        for (int j = 0; j < 8; ++j) acc[i][j] = 0.f;

    for (int k0 = 0; k0 < DD; k0 += BK) {
        float4 av = *reinterpret_cast<const float4*>(
            &A[(size_t)(row0 + ar) * DD + k0 + ac]);
        float4 bv = *reinterpret_cast<const float4*>(
            &B[(size_t)(k0 + br) * HH + col0 + bc]);

        As[ac + 0][ar] = av.x;
        As[ac + 1][ar] = av.y;
        As[ac + 2][ar] = av.z;
        As[ac + 3][ar] = av.w;
        *reinterpret_cast<float4*>(&Bs[br][bc]) = bv;
        __syncthreads();

#pragma unroll
        for (int kk = 0; kk < BK; ++kk) {
            float a[8], b[8];
            *reinterpret_cast<float4*>(&a[0]) =
                *reinterpret_cast<const float4*>(&As[kk][tm * 8]);
            *reinterpret_cast<float4*>(&a[4]) =
                *reinterpret_cast<const float4*>(&As[kk][tm * 8 + 4]);
            *reinterpret_cast<float4*>(&b[0]) =
                *reinterpret_cast<const float4*>(&Bs[kk][tn * 8]);
            *reinterpret_cast<float4*>(&b[4]) =
                *reinterpret_cast<const float4*>(&Bs[kk][tn * 8 + 4]);
#pragma unroll
            for (int i = 0; i < 8; ++i)
#pragma unroll
                for (int j = 0; j < 8; ++j)
                    acc[i][j] = fmaf(a[i], b[j], acc[i][j]);
        }
        __syncthreads();
    }

#pragma unroll
    for (int i = 0; i < 8; ++i) {
        const int row = row0 + tm * 8 + i;
#pragma unroll
        for (int j = 0; j < 8; j += 4) {
            const int col = col0 + tn * 8 + j;
            float4 o;
            o.x = acc[i][j + 0] + bias[col + 0];
            o.y = acc[i][j + 1] + bias[col + 1];
            o.z = acc[i][j + 2] + bias[col + 2];
            o.w = acc[i][j + 3] + bias[col + 3];
            *reinterpret_cast<float4*>(&C[(size_t)row * HH + col]) = o;
        }
    }
}

// ---------------------------------------------------------------------------
// Kernel 2: scan, fp16-weight dot2 version.
// 64 blocks (one per batch), 1024 threads = 16 waves (4/SIMD).
// Thread (j = tid&511, half = tid>>9) computes a half-K partial of column j:
//   128 packed pairs = 32 groups of {1 dwordx4 W load, 1 b128 LDS h read,
//   4 v_dot2_f32_f16}.  Partials reduced through LDS; tanh by tid<512.
// h kept as packed fp16 in LDS (double-buffered); xw prefetched per step.
// ---------------------------------------------------------------------------
__global__ __launch_bounds__(1024, 4) void rnn_scan_f16(
    const uint32_t* __restrict__ Wt,  // packed fp16 pairs, swizzled
    const float* __restrict__ h0,     // (N, H)
    float* __restrict__ out)          // (N, T, H): in = xw, out = h
{
    __shared__ __align__(16) uint32_t hpk[2][K2];   // packed fp16 h
    __shared__ float partial[2][HH];

    const int tid  = threadIdx.x;
    const int j    = tid & (HH - 1);
    const int half = tid >> 9;
    const int n    = blockIdx.x;
    float* outn = out + (size_t)n * TT * HH;

    if (tid < HH)
        ((__half*)hpk[0])[tid] = __float2half(h0[(size_t)n * HH + tid]);
    __syncthreads();

    const uint4* wbase =
        (const uint4*)Wt + (size_t)half * 32 * HH + j;  // float4-granular idx

    int cur = 0;
    for (int t = 0; t < TT; ++t) {
        // prefetch this step's xw early; consumed after the barrier
        float xw_r = (tid < HH) ? outn[(size_t)t * HH + tid] : 0.f;

        const uint32_t* hp = &hpk[cur][half * 128];
        float a0 = 0.f, a1 = 0.f, a2 = 0.f, a3 = 0.f;
#pragma unroll 8
        for (int g = 0; g < 32; ++g) {
            uint4 wv = wbase[(size_t)g * HH];           // coalesced 16B/lane
            uint4 hv = *(const uint4*)&hp[g * 4];       // wave-uniform bcast
            a0 = dot2f(hv.x, wv.x, a0);
            a1 = dot2f(hv.y, wv.y, a1);
            a2 = dot2f(hv.z, wv.z, a2);
            a3 = dot2f(hv.w, wv.w, a3);
        }
        partial[half][j] = (a0 + a1) + (a2 + a3);
        __syncthreads();

        if (tid < HH) {
            float z = partial[0][tid] + partial[1][tid] + xw_r;
            float h = tanhf(z);
            outn[(size_t)t * HH + tid] = h;
            ((__half*)hpk[cur ^ 1])[tid] = __float2half(h);
        }
        __syncthreads();
        cur ^= 1;
    }
}

// ---------------------------------------------------------------------------
// Fallback scan (fp32 weights from d_in) in case d_ws is too small.
// ---------------------------------------------------------------------------
__global__ __launch_bounds__(512, 2) void rnn_scan_f32(
    const float* __restrict__ Wh,
    const float* __restrict__ h0,
    float* __restrict__ out)
{
    __shared__ float hbuf[2][HH];
    const int n = blockIdx.x;
    const int j = threadIdx.x;

    hbuf[0][j] = h0[(size_t)n * HH + j];
    __syncthreads();

    float* outn = out + (size_t)n * TT * HH;
    const float* __restrict__ wp = Wh + j;

    int cur = 0;
    for (int t = 0; t < TT; ++t) {
        float acc = outn[(size_t)t * HH + j];
        const float* hc = hbuf[cur];
#pragma unroll 4
        for (int k = 0; k < HH; k += 4) {
            float4 hv = *reinterpret_cast<const float4*>(&hc[k]);
            acc = fmaf(hv.x, wp[(size_t)(k + 0) * HH], acc);
            acc = fmaf(hv.y, wp[(size_t)(k + 1) * HH], acc);
            acc = fmaf(hv.z, wp[(size_t)(k + 2) * HH], acc);
            acc = fmaf(hv.w, wp[(size_t)(k + 3) * HH], acc);
        }
        float hn = tanhf(acc);
        outn[(size_t)t * HH + j] = hn;
        hbuf[cur ^ 1][j] = hn;
        cur ^= 1;
        __syncthreads();
    }
}

// ---------------------------------------------------------------------------
extern "C" void kernel_launch(void* const* d_in, const int* in_sizes, int n_in,
                              void* d_out, int out_size, void* d_ws, size_t ws_size,
                              hipStream_t stream) {
    const float* x  = (const float*)d_in[0];   // (N, T, D)
    const float* h0 = (const float*)d_in[1];   // (N, H)
    const float* Wx = (const float*)d_in[2];   // (D, H)
    const float* Wh = (const float*)d_in[3];   // (H, H)
    const float* b  = (const float*)d_in[4];   // (H)
    float* out = (float*)d_out;                // (N, T, H)

    dim3 g1((NB * TT) / BM, HH / BN);
    gemm_xw<<<g1, 256, 0, stream>>>(x, Wx, b, out);

    const size_t wt_bytes = (size_t)K2 * HH * sizeof(uint32_t);  // 512 KB
    if (ws_size >= wt_bytes) {
        conv_wh<<<(K2 * HH) / 256, 256, 0, stream>>>(Wh, (uint32_t*)d_ws);
        rnn_scan_f16<<<NB, 1024, 0, stream>>>((const uint32_t*)d_ws, h0, out);
    } else {
        rnn_scan_f32<<<NB, 512, 0, stream>>>(Wh, h0, out);
    }
}